// Round 5
// baseline (340.052 us; speedup 1.0000x reference)
//
#include <hip/hip_runtime.h>

// QRNN3D fused: conv3d(16->48,3x3x3,SAME) + gates + fo-pool via bf16 MFMA.
// Round 8 = round 7 resubmit (infra failure, no measurement) + fix of a
// prologue store/store race: ring slots are 408 units (not 256-aligned), so
// zero-fill and plane-write of the same unit can come from DIFFERENT threads
// -> need a BARRIER between zeroing and the plane-0/1 writes.
// Round 7 (from 135us/dispatch, LDS pipe 44% = top resource, 59% of LDS
// traffic = per-t weight re-reads):
//  - g=0,1 weight A-frags (28 frags = 112 VGPR) live in REGISTERS, loaded
//    once from global (L2/L3-resident). g=2 stays in LDS (14336B). Weight
//    LDS traffic per block-t: 172KB -> 57KB; total LDS 293 -> 178KB.
//  - lds_write moved to TOP of body: with NSLOT=4, slot r3's last reader
//    was iteration t-1 (barrier-protected), so the plane-(t+2) write may
//    precede the MFMA block and drain in its shadow. rv is a SINGLE buffer
//    with unchanged one-full-iteration load depth.
//  - LDS static 40448B (<64K); one barrier per t.
//
// GEMM: gates[48][px] = W[48][K=448] * im2col[K][px]; K = tap*16+ic,
// tap = kd*9+kh*3+kw (27 real, pad tap 27 has W==0).
// mfma_f32_16x16x32_bf16: A[m][k=q*8+j] = W, B[k][n=px], C/D col=lane&15,
// row=q*4+reg. Wave owns 32 px x 16 hidden ch; z/f/o accs lane-aligned so
// the t-recurrence is per-lane register math.

typedef __attribute__((ext_vector_type(8))) short short8;
typedef __attribute__((ext_vector_type(4))) float float4v;

#define TD 31
#define HW (128 * 128)
#define LH 6                         // 4 tile rows + 2 halo
#define LW 34                        // 32 tile cols + 2 halo
#define UNITS (LH * 2 * LW)          // 408 short8 units per plane
#define NSLOT 4
#define SLOTB (UNITS * 16)           // 6528 B per ring slot
#define W2UNITS (14 * 64)            // g=2 weight units (14336 B)

__device__ __forceinline__ short f2bf(float f) {
    unsigned u = __float_as_uint(f);
    u = (u + 0x7FFFu + ((u >> 16) & 1u)) >> 16;   // RNE
    return (short)u;
}

__device__ __forceinline__ float frcp(float x) { return __builtin_amdgcn_rcpf(x); }

__device__ __forceinline__ unsigned cvtpk(float lo, float hi) {
    unsigned r;
    asm("v_cvt_pk_bf16_f32 %0, %1, %2" : "=v"(r) : "v"(lo), "v"(hi));
    return r;
}

// Barrier WITHOUT the compiler's vmcnt(0) drain. lgkmcnt(0) orders LDS;
// global loads target private registers (compiler-tracked vmcnt at use).
#define BARRIER() asm volatile("s_waitcnt lgkmcnt(0)\n\ts_barrier" ::: "memory")

__global__ __launch_bounds__(256, 2) void qrnn_mfma5(
    const float* __restrict__ x,     // (4,16,31,128,128)
    const float* __restrict__ wt,    // (48,16,27)
    const float* __restrict__ bias,  // (48)
    float* __restrict__ out)         // (4,16,31,128,128)
{
    __shared__ short8 wlds2[W2UNITS];        // 14336 B (g=2 A-frags)
    __shared__ short8 ring[NSLOT * UNITS];   // 26112 B  -> total 40448 B

    const int tid  = threadIdx.x;
    const int lane = tid & 63;
    const int wv   = tid >> 6;       // wave id = h row in tile
    const int q    = lane >> 4;
    const int px   = lane & 15;
    const int b    = blockIdx.x;     // 512 blocks
    const int n    = b >> 7;
    const int h0   = ((b >> 2) & 31) * 4;
    const int w0   = (b & 3) * 32;

    const float* xin = x + (size_t)n * (16 * TD * HW);

    // ---- g=0,1 weight A-frags -> registers (28 frags, 112 VGPR).
    //      A-frag row m = lane&15 = px; k = q*8+j within the s-step. ----
    short8 wreg[2][14];
#pragma unroll
    for (int g = 0; g < 2; ++g)
#pragma unroll
        for (int s = 0; s < 14; ++s) {
            short8 a;
#pragma unroll
            for (int j = 0; j < 8; ++j) {
                int kk = s * 32 + q * 8 + j;
                int tap = kk >> 4, ic = kk & 15;
                float v = (tap < 27) ? wt[((size_t)((g * 16 + px) * 16 + ic)) * 27 + tap] : 0.f;
                a[j] = f2bf(v);
            }
            wreg[g][s] = a;
        }

    // ---- g=2 weight A-frags -> LDS: wlds2[s*64 + lane] ----
    for (int k = 0; k < 4; ++k) {
        int u = tid + k * 256;
        if (u < W2UNITS) {
            int l = u & 63, s = u >> 6;
            int qq = l >> 4, m = l & 15;
            short8 a;
#pragma unroll
            for (int j = 0; j < 8; ++j) {
                int kk = s * 32 + qq * 8 + j;
                int tap = kk >> 4, ic = kk & 15;
                float v = (tap < 27) ? wt[((size_t)((32 + m) * 16 + ic)) * 27 + tap] : 0.f;
                a[j] = f2bf(v);
            }
            wlds2[u] = a;
        }
    }
    // ---- zero all ring slots once (halo-invalid units stay 0 forever;
    //      plane -1 = slot 3 stays 0) ----
    {
        short8 z = (short8)0;
        for (int k = 0; k < 7; ++k) {
            int u = tid + k * 256;
            if (u < NSLOT * UNITS) ring[u] = z;
        }
    }

    // ---- staging: 1 VGPR voffset per unit + 8 uniform SGPR plane bases ----
    unsigned voff[2];
    bool s_ok[2];
#pragma unroll
    for (int i = 0; i < 2; ++i) {
        int u    = tid + i * 256;
        int uu   = (u < UNITS) ? u : 0;
        int wp   = uu % LW;
        int rest = uu / LW;
        int ck   = rest & 1;
        int hp   = rest >> 1;
        int hh   = h0 + hp - 1;
        int ww   = w0 + wp - 1;
        s_ok[i] = (u < UNITS) && ((unsigned)hh < 128u) && ((unsigned)ww < 128u);
        int hc = hh < 0 ? 0 : (hh > 127 ? 127 : hh);   // clamped safe coords
        int wc = ww < 0 ? 0 : (ww > 127 ? 127 : ww);
        voff[i] = (unsigned)(ck * (8 * TD * HW) + hc * 128 + wc);
    }

    float rv[2][8];                  // single staging buffer

    // loads ALWAYS issued at safe clamped addresses; saddr-form:
    // uniform base (xin + tc*HW + j*TD*HW) + per-lane 32-bit voffset.
    auto issue = [&](int tt) {
        const int tc = ((unsigned)tt >= 31u) ? 0 : tt;
        const float* basep = xin + (size_t)tc * HW;
#pragma unroll
        for (int j = 0; j < 8; ++j) {
            const float* bj = basep + (size_t)j * (TD * HW);   // uniform
            rv[0][j] = bj[voff[0]];
            rv[1][j] = bj[voff[1]];
        }
    };

    // tz is wave-uniform: zero-write path is a uniform branch (t>=29 only).
    auto lds_write = [&](int wu, bool tz) {
        if (!tz) {
#pragma unroll
            for (int i = 0; i < 2; ++i) {
                if (s_ok[i]) {
                    union { short8 s; unsigned u[4]; } v;
#pragma unroll
                    for (int k = 0; k < 4; ++k)
                        v.u[k] = cvtpk(rv[i][2 * k], rv[i][2 * k + 1]);
                    ring[wu + tid + i * 256] = v.s;
                }
            }
        } else {
            short8 z = (short8)0;
#pragma unroll
            for (int i = 0; i < 2; ++i)
                if (s_ok[i]) ring[wu + tid + i * 256] = z;
        }
    };

    // ---- ring tap offsets (t-invariant). kd compile-time except s=4. ----
    int roff[14];
#pragma unroll
    for (int s = 0; s < 14; ++s) {
        int T = 2 * s + (q >> 1); if (T > 26) T = 26;
        int kd = T / 9, rr = T - kd * 9, kh = rr / 3, kw = rr - kh * 3;
        roff[s] = (((wv + kh) * 2 + (q & 1)) * LW + px + kw) * 16;  // bytes
    }
    const int kd4 = q >> 1;          // kd for s==4: taps 8 (kd=0) / 9 (kd=1)

    // bias per lane: channel = g*16 + q*4 + r
    float4v bv[3];
#pragma unroll
    for (int g = 0; g < 3; ++g)
        bv[g] = (float4v){bias[g * 16 + q * 4 + 0], bias[g * 16 + q * 4 + 1],
                          bias[g * 16 + q * 4 + 2], bias[g * 16 + q * 4 + 3]};

    float* po = out + ((size_t)(n * 16 + q * 4) * TD) * HW
                    + (size_t)(h0 + wv) * 128 + w0 + px;
    float cst[2][4] = {{0.f,0.f,0.f,0.f},{0.f,0.f,0.f,0.f}};

    // ---- prologue. slot(p) = p&3; plane -1 -> slot 3 (zeros).
    //      Ring slots are 408 units (NOT 256-aligned): the zero-fill of a
    //      unit and its plane-write can come from different threads ->
    //      barrier between them is REQUIRED. ----
    BARRIER();
    issue(0); lds_write(0 * UNITS, false);
    issue(1); lds_write(1 * UNITS, false);
    issue(2);                        // rv = plane 2, written by body(0)
    BARRIER();

    // body(t): slots r0..r3 hold planes t-1..t+2. Write plane t+2 (from rv,
    // issued at t-1) into r3 FIRST — r3's last reader was t-1 (barriered) —
    // then refill rv with plane t+3; MFMA block reads r0..r2 meanwhile.
    int r0 = 3 * SLOTB, r1 = 0, r2 = SLOTB, r3 = 2 * SLOTB;
    for (int t = 0; t < TD; ++t) {
        lds_write(r3 >> 4, t >= 29);     // plane t+2 (zeros for t>=29)
        issue(t + 3);                    // in flight until body(t+1)

        float4v acc[2][3];
#pragma unroll
        for (int g = 0; g < 3; ++g) { acc[0][g] = bv[g]; acc[1][g] = bv[g]; }

        const int pk[3] = {r0, r1, r2};
        constexpr int kdt[14] = {0,0,0,0, 0 /*s=4 special*/, 1,1,1,1, 2,2,2,2,2};
        const char* ringb = (const char*)ring;
#pragma unroll
        for (int s = 0; s < 14; ++s) {
            int sb = (s == 4) ? (kd4 ? r1 : r0) : pk[kdt[s]];
            const short8* bp = (const short8*)(ringb + sb + roff[s]);
            short8 wf2 = wlds2[s * 64 + lane];   // g=2 frag (LDS)
            short8 b0 = bp[0];           // ds_read_b128, conflict-free
            short8 b1 = bp[16];          // +16 w cols, offset:256 immediate
            acc[0][0] = __builtin_amdgcn_mfma_f32_16x16x32_bf16(wreg[0][s], b0, acc[0][0], 0, 0, 0);
            acc[1][0] = __builtin_amdgcn_mfma_f32_16x16x32_bf16(wreg[0][s], b1, acc[1][0], 0, 0, 0);
            acc[0][1] = __builtin_amdgcn_mfma_f32_16x16x32_bf16(wreg[1][s], b0, acc[0][1], 0, 0, 0);
            acc[1][1] = __builtin_amdgcn_mfma_f32_16x16x32_bf16(wreg[1][s], b1, acc[1][1], 0, 0, 0);
            acc[0][2] = __builtin_amdgcn_mfma_f32_16x16x32_bf16(wf2, b0, acc[0][2], 0, 0, 0);
            acc[1][2] = __builtin_amdgcn_mfma_f32_16x16x32_bf16(wf2, b1, acc[1][2], 0, 0, 0);
        }

        // activations + fo-pool + store (rcp fast path)
#pragma unroll
        for (int tile = 0; tile < 2; ++tile) {
#pragma unroll
            for (int r = 0; r < 4; ++r) {
                float az = acc[tile][0][r];
                float af = acc[tile][1][r];
                float ao = acc[tile][2][r];
                float z = 1.f - 2.f * frcp(__expf(2.f * az) + 1.f);
                float f = frcp(1.f + __expf(-af));
                float o = frcp(1.f + __expf(-ao));
                float c = f * cst[tile][r] + (1.f - f) * z;
                cst[tile][r] = c;
                po[(size_t)r * (TD * HW) + tile * 16] = o * c;
            }
        }
        po += HW;
        BARRIER();   // my reads of r0..r2 done (lgkmcnt 0) + write of r3
                     // visible -> next iter may read r3's plane & reuse r0
        int tmp = r0; r0 = r1; r1 = r2; r2 = r3; r3 = tmp;
    }
}

extern "C" void kernel_launch(void* const* d_in, const int* in_sizes, int n_in,
                              void* d_out, int out_size, void* d_ws, size_t ws_size,
                              hipStream_t stream) {
    const float* x    = (const float*)d_in[0];
    const float* wt   = (const float*)d_in[1];
    const float* bias = (const float*)d_in[2];
    float* out = (float*)d_out;

    // grid: n(4) x hblk(32) x wblk(4) = 512 blocks of 256 threads (4 waves)
    qrnn_mfma5<<<dim3(512), dim3(256), 0, stream>>>(x, wt, bias, out);
}